// Round 1
// baseline (63.629 us; speedup 1.0000x reference)
//
#include <hip/hip_runtime.h>

#define TILE   32
#define HALO   2
#define LW     (TILE + 2*HALO)   // 36
#define IMG_H  512
#define IMG_W  512
#define NBATCH 8
// mean denominator: B * 8 dirs * H * W
#define N_MEAN 16777216.0

__device__ __forceinline__ float frcp(float x) { return __builtin_amdgcn_rcpf(x); }

__global__ __launch_bounds__(256) void scloss_main(
    const float* __restrict__ cmap, const int* __restrict__ tgt,
    float* __restrict__ partials)
{
    __shared__ float s_lds[LW * LW];
    __shared__ int   t_lds[LW * LW];

    const int tilesPerRow = IMG_W / TILE;               // 16
    const int tilesPerImg = (IMG_H / TILE) * tilesPerRow; // 256
    int blk = blockIdx.x;
    int b   = blk / tilesPerImg;
    int ti  = blk % tilesPerImg;
    int tr  = (ti / tilesPerRow) * TILE;
    int tcl = (ti % tilesPerRow) * TILE;

    const float* cimg = cmap + (size_t)b * IMG_H * IMG_W;
    const int*   timg = tgt  + (size_t)b * IMG_H * IMG_W;

    // Stage tile + halo: sigmoid(c_map) and target (sentinel 2 for OOB).
    for (int idx = threadIdx.x; idx < LW * LW; idx += 256) {
        int lr = idx / LW, lc = idx - lr * LW;
        int gr = tr + lr - HALO, gc = tcl + lc - HALO;
        float s = 0.0f; int t = 2;
        if (gr >= 0 && gr < IMG_H && gc >= 0 && gc < IMG_W) {
            float x = cimg[gr * IMG_W + gc];
            s = frcp(1.0f + __expf(-x));
            t = timg[gr * IMG_W + gc];
        }
        s_lds[idx] = s;
        t_lds[idx] = t;
    }
    __syncthreads();

    float acc = 0.0f;
    #pragma unroll
    for (int pi = 0; pi < 4; ++pi) {
        int p  = pi * 256 + threadIdx.x;
        int rr = (p >> 5) + HALO;
        int cc = (p & 31) + HALO;
        float s  = s_lds[rr * LW + cc];
        int   tc = t_lds[rr * LW + cc];
        #pragma unroll
        for (int K = 1; K <= 2; ++K) {
            const float wpos = (K == 1) ? 0.3f : 0.15f;
            const float wneg = (K == 1) ? 0.7f : 0.35f;
            #pragma unroll
            for (int dr = -1; dr <= 1; ++dr) {
                #pragma unroll
                for (int dc = -1; dc <= 1; ++dc) {
                    if (dr == 0 && dc == 0) continue;
                    int off  = (rr + dr * K) * LW + (cc + dc * K);
                    float sn = s_lds[off];
                    int   tn = t_lds[off];
                    bool pos = (tc == 1) && (tn == 1);
                    bool neg = (tc == 0) && (tn == 0);
                    bool nbr = (tc == 1) && (tn == 0);
                    float pp   = s * sn;
                    float argA = pos ? (sn + 1e-4f) : (1.0f - sn + 1e-4f);
                    float argB = pos ? (s + 1e-4f)
                                     : (nbr ? (s + 1e-5f) : (1.0f - s + 1e-4f));
                    float argC = pos ? (pp + 1e-4f) : (1.0f - pp + 1e-4f);
                    float argE = nbr ? -sn : -pp;
                    float cA   = nbr ? 0.8f : 1.0f;
                    float cB   = nbr ? 0.2f : 1.0f;
                    float w    = pos ? wpos : (neg ? wneg : (nbr ? 0.35f : 0.0f));
                    float t1 = -(cA * __logf(argA) + cB * __logf(argB));
                    float t2 = __expf(argE) - __logf(argC);
                    acc += w * t1 * frcp(t2 + 1e-5f);
                }
            }
        }
    }

    // Block reduction: wave64 shuffle then cross-wave via LDS.
    #pragma unroll
    for (int o = 32; o > 0; o >>= 1) acc += __shfl_down(acc, o, 64);
    __shared__ float wsum[4];
    int lane = threadIdx.x & 63, wid = threadIdx.x >> 6;
    if (lane == 0) wsum[wid] = acc;
    __syncthreads();
    if (threadIdx.x == 0)
        partials[blockIdx.x] = wsum[0] + wsum[1] + wsum[2] + wsum[3];
}

__global__ __launch_bounds__(256) void scloss_final(
    const float* __restrict__ partials, int n, float* __restrict__ out)
{
    double a = 0.0;
    for (int i = threadIdx.x; i < n; i += 256) a += (double)partials[i];
    __shared__ double sd[256];
    sd[threadIdx.x] = a;
    __syncthreads();
    for (int s = 128; s > 0; s >>= 1) {
        if (threadIdx.x < s) sd[threadIdx.x] += sd[threadIdx.x + s];
        __syncthreads();
    }
    if (threadIdx.x == 0) out[0] = (float)(sd[0] / N_MEAN);
}

extern "C" void kernel_launch(void* const* d_in, const int* in_sizes, int n_in,
                              void* d_out, int out_size, void* d_ws, size_t ws_size,
                              hipStream_t stream) {
    const float* cmap = (const float*)d_in[0];
    const int*   tgt  = (const int*)d_in[1];
    float* out      = (float*)d_out;
    float* partials = (float*)d_ws;

    int nblocks = NBATCH * (IMG_H / TILE) * (IMG_W / TILE); // 2048
    scloss_main<<<nblocks, 256, 0, stream>>>(cmap, tgt, partials);
    scloss_final<<<1, 256, 0, stream>>>(partials, nblocks, out);
}

// Round 2
// 30.277 us; speedup vs baseline: 2.1015x; 2.1015x over previous
//
#include <hip/hip_runtime.h>

#define IMG_H 512
#define IMG_W 512
#define NB    8
#define TILE  32
#define LROWS 34            // owner rows 0..31 + 2 halo rows below
#define LCOLS 36            // owner col j -> lds col j+2 (halo +-2)
#define N_MEAN 16777216.0   // B * 8 dirs * H * W

__device__ __forceinline__ float frcp(float x){ return __builtin_amdgcn_rcpf(x); }

// Per-pixel pack: {s, m, e', k}
//   s  = sigmoid(c_map)
//   m  = t ? log(s+1e-4) : log(1-s+1e-4)
//   e' = (t ? -1 : +1) * exp(-s);  e' == 0  => OOB sentinel
//   k  = t ? 0.2 : 0.8   (neighbor-loss per-endpoint log coefficient)
__global__ __launch_bounds__(256) void scloss_main(
    const float* __restrict__ cmap, const int* __restrict__ tgt,
    float* __restrict__ partials)
{
    __shared__ float4 pack[LROWS * LCOLS];

    const int tilesPerRow = IMG_W / TILE;                 // 16
    const int tilesPerImg = (IMG_H / TILE) * tilesPerRow; // 256
    int blk = blockIdx.x;
    int b   = blk / tilesPerImg;
    int ti  = blk % tilesPerImg;
    int tr  = (ti / tilesPerRow) * TILE;
    int tc  = (ti % tilesPerRow) * TILE;

    const float* cimg = cmap + (size_t)b * (IMG_H * IMG_W);
    const int*   timg = tgt  + (size_t)b * (IMG_H * IMG_W);

    // Stage global rows tr..tr+33, cols tc-2..tc+33.
    for (int idx = threadIdx.x; idx < LROWS * LCOLS; idx += 256) {
        int lr = idx / LCOLS, lc = idx - lr * LCOLS;
        int gr = tr + lr, gc = tc + lc - 2;
        float4 v = make_float4(0.0f, 0.0f, 0.0f, 0.8f);
        if (gr < IMG_H && (unsigned)gc < (unsigned)IMG_W) {
            float x = cimg[gr * IMG_W + gc];
            bool  t = timg[gr * IMG_W + gc] != 0;
            float s = frcp(1.0f + __expf(-x));
            float sel = t ? s : (1.0f - s);
            float m = __logf(sel + 1e-4f);
            float e = __expf(-s);
            v = make_float4(s, m, t ? -e : e, t ? 0.2f : 0.8f);
        }
        pack[idx] = v;
    }
    __syncthreads();

    int j  = threadIdx.x & 31;
    int i0 = threadIdx.x >> 5;      // 0..7
    float acc = 0.0f;

    #pragma unroll
    for (int pi = 0; pi < 4; ++pi) {
        int i = i0 + pi * 8;
        const float4* base = &pack[i * LCOLS + (j + 2)];
        float4 va = base[0];
        bool  ta  = va.z < 0.0f;            // target of owner pixel
        float sa  = va.x, ma = va.y, epa = va.z;
        float ea  = fabsf(va.z);
        float kaa = va.w;                   // t_a ? 0.2 : 0.8
        float wEq1 = ta ? -0.6f : -1.4f;    // 2 * {0.3 pos | 0.7 neg}, negated
        float wEq2 = ta ? -0.3f : -0.7f;    // 2 * {0.15 | 0.35}, negated

        #pragma unroll
        for (int K = 1; K <= 2; ++K) {
            float wEq = (K == 1) ? wEq1 : wEq2;
            // owned dirs: E(0,1) SE(1,1) S(1,0) SW(1,-1)
            const int offs[4] = { 1, LCOLS + 1, LCOLS, LCOLS - 1 };
            #pragma unroll
            for (int d = 0; d < 4; ++d) {
                float4 vb = base[offs[d] * K];
                float q   = epa * vb.z;          // sign: >0 eq, <0 neq, ==0 OOB
                float pp  = sa * vb.x;
                bool qpos = q > 0.0f;
                float omp  = 1.0f - pp;
                float c0   = ta ? pp : omp;
                float argC = qpos ? c0 : omp;
                float lc   = __logf(argC + 1e-4f) - 1e-5f;
                float E    = __expf(-pp);
                float eb   = fabsf(vb.z);
                float een  = ta ? eb : ea;       // e of the t=0 endpoint (neq)
                float ee   = qpos ? E : een;
                float r    = frcp(ee - lc);      // 1/(term2 + 1e-5)
                float kb   = qpos ? 1.0f : vb.w;
                float ka   = qpos ? 1.0f : kaa;
                float t1   = ka * ma + kb * vb.y;   // = -(term1)
                float wq   = qpos ? wEq : -0.35f;
                float w    = (q != 0.0f) ? wq : 0.0f;
                acc += (w * t1) * r;
            }
        }
    }

    // Block reduction: wave64 shuffle then cross-wave via LDS.
    #pragma unroll
    for (int o = 32; o > 0; o >>= 1) acc += __shfl_down(acc, o, 64);
    __shared__ float wsum[4];
    int lane = threadIdx.x & 63, wid = threadIdx.x >> 6;
    if (lane == 0) wsum[wid] = acc;
    __syncthreads();
    if (threadIdx.x == 0)
        partials[blockIdx.x] = wsum[0] + wsum[1] + wsum[2] + wsum[3];
}

__global__ __launch_bounds__(256) void scloss_final(
    const float* __restrict__ partials, int n, float* __restrict__ out)
{
    double a = 0.0;
    for (int i = threadIdx.x; i < n; i += 256) a += (double)partials[i];
    __shared__ double sd[256];
    sd[threadIdx.x] = a;
    __syncthreads();
    for (int s = 128; s > 0; s >>= 1) {
        if (threadIdx.x < s) sd[threadIdx.x] += sd[threadIdx.x + s];
        __syncthreads();
    }
    if (threadIdx.x == 0) out[0] = (float)(sd[0] / N_MEAN);
}

extern "C" void kernel_launch(void* const* d_in, const int* in_sizes, int n_in,
                              void* d_out, int out_size, void* d_ws, size_t ws_size,
                              hipStream_t stream) {
    const float* cmap = (const float*)d_in[0];
    const int*   tgt  = (const int*)d_in[1];
    float* out      = (float*)d_out;
    float* partials = (float*)d_ws;

    int nblocks = NB * (IMG_H / TILE) * (IMG_W / TILE); // 2048
    scloss_main<<<nblocks, 256, 0, stream>>>(cmap, tgt, partials);
    scloss_final<<<1, 256, 0, stream>>>(partials, nblocks, out);
}